// Round 8
// baseline (296.546 us; speedup 1.0000x reference)
//
#include <hip/hip_runtime.h>

typedef unsigned short u16;
typedef short bf16x8 __attribute__((ext_vector_type(8)));
typedef float f32x4 __attribute__((ext_vector_type(4)));

__device__ inline u16 f32_to_bf16(float f) {
  union { float f; unsigned int u; } v; v.f = f;
  unsigned int r = v.u + 0x7FFFu + ((v.u >> 16) & 1u);
  return (u16)(r >> 16);
}

// 16-lane butterfly sum via __shfl_xor (HW-proven) — used ONCE per kernel.
__device__ inline float red16_sum(float x) {
#pragma unroll
  for (int m = 8; m >= 1; m >>= 1) x += __shfl_xor(x, m);
  return x;
}

// async global->LDS, 16B per lane; LDS dest = wave-uniform base + lane*16.
__device__ __forceinline__ void gl_lds16(const u16* g, u16* l) {
  __builtin_amdgcn_global_load_lds(
      (const __attribute__((address_space(1))) void*)g,
      (__attribute__((address_space(3))) void*)l, 16, 0, 0);
}

// ------- x convert: f32 -> bf16, 8 elems/thread -------
__global__ __launch_bounds__(256) void xcvt_kernel(const float* __restrict__ in,
                                                   u16* __restrict__ out) {
  size_t i = (size_t)blockIdx.x * 256 + threadIdx.x;
  float4 f0 = ((const float4*)in)[2 * i];
  float4 f1 = ((const float4*)in)[2 * i + 1];
  union { u16 t[8]; uint4 v; } pk;
  pk.t[0] = f32_to_bf16(f0.x); pk.t[1] = f32_to_bf16(f0.y);
  pk.t[2] = f32_to_bf16(f0.z); pk.t[3] = f32_to_bf16(f0.w);
  pk.t[4] = f32_to_bf16(f1.x); pk.t[5] = f32_to_bf16(f1.y);
  pk.t[6] = f32_to_bf16(f1.z); pk.t[7] = f32_to_bf16(f1.w);
  ((uint4*)out)[i] = pk.v;
}

// ------- 4x transpose+convert 1024x1024 (z = which matrix) -------
__global__ __launch_bounds__(256) void transpose_cvt4_kernel(const float* __restrict__ i0,
                                                             const float* __restrict__ i1,
                                                             const float* __restrict__ i2,
                                                             const float* __restrict__ i3,
                                                             u16* __restrict__ wbase) {
  const int z = blockIdx.z;
  const float* in = (z == 0) ? i0 : (z == 1) ? i1 : (z == 2) ? i2 : i3;
  u16* out = wbase + (size_t)z * (1 << 20);
  __shared__ __align__(16) float tile[32][33];
  const int tx = threadIdx.x & 31, ty = threadIdx.x >> 5; // 32 x 8
  const int bx = blockIdx.x * 32, by = blockIdx.y * 32;
#pragma unroll
  for (int i = 0; i < 32; i += 8)
    tile[ty + i][tx] = in[(size_t)(by + ty + i) * 1024 + bx + tx];
  __syncthreads();
#pragma unroll
  for (int i = 0; i < 32; i += 8)
    out[(size_t)(bx + ty + i) * 1024 + by + tx] = f32_to_bf16(tile[tx][ty + i]);
}

// ======================================================================
// fused QKV GEMM — R8: 128x256 tile (clone of the validated R7 gemm_out
// structure) -> grid 12x64 = 768 blocks = EXACTLY 3.0 balanced rounds.
// R2/R4 span was pinned at 2.0 x T_block (384 blocks @ 1 block/CU: half
// the CUs idle for half the kernel).  Same staging rows / XOR swizzle /
// khalf strides / free-run single-barrier loop as R4+R7 (conflicts=0
// pedigree); only tile M halves.  LDS 96 KiB: A 2x2x[128x32] + B
// 2x2x[256x32].  8 waves (2M x 4N), per-wave 64x64 -> acc[4][4].
// Epilogue proj logic unchanged from R4 (N-tile stays 256).
// ======================================================================

#define QKV_BAR asm volatile("s_barrier" ::: "memory")
#define QKV_VMW(n) asm volatile("s_waitcnt vmcnt(" #n ")" ::: "memory")
#define QKV_LGK0 asm volatile("s_waitcnt lgkmcnt(0)" ::: "memory")
#define SCHED0 __builtin_amdgcn_sched_barrier(0)

// asm ds_read_b128: dst = 4-VGPR tuple, addr = LDS byte address, literal offset
#define DSR(dst, addr, off) \
  asm volatile("ds_read_b128 %0, %1 offset:" #off : "=v"(dst) : "v"(addr))

// 64 B rows (one khalf); frags 16 rows apart -> 1024 B
#define LDA_ALL(ad) { DSR(afr[0], ad, 0);    DSR(afr[1], ad, 1024); \
                      DSR(afr[2], ad, 2048); DSR(afr[3], ad, 3072); }
#define LDB_ALL(bd) { DSR(bfr[0], bd, 0);    DSR(bfr[1], bd, 1024); \
                      DSR(bfr[2], bd, 2048); DSR(bfr[3], bd, 3072); }

#define STAGE_A(d2, kh, kt)                                        \
    gl_lds16(A + aSrc + (size_t)(kt) * 64 + (kh) * 32,             \
             &sA[d2][kh][wave * 512])
#define STAGE_B(d2, kh, kt) do {                                   \
    const u16* _p = Bt + bSrc + (size_t)(kt) * 64 + (kh) * 32;     \
    gl_lds16(_p, &sB[d2][kh][wave * 1024]);                        \
    gl_lds16(_p + 16 * 1024, &sB[d2][kh][wave * 1024 + 512]);      \
  } while (0)
#define MMA4 {                                                     \
    _Pragma("unroll") for (int mt = 0; mt < 4; ++mt)               \
      _Pragma("unroll") for (int nt = 0; nt < 4; ++nt)             \
        acc[mt][nt] = __builtin_amdgcn_mfma_f32_16x16x32_bf16(     \
            afr[mt], bfr[nt], acc[mt][nt], 0, 0, 0); }

__global__ __launch_bounds__(512, 2) void gemm_qkv_kernel(const u16* __restrict__ A,
                                                          const u16* __restrict__ Bt,
                                                          u16* __restrict__ Q,
                                                          u16* __restrict__ K,
                                                          u16* __restrict__ Vt) {
  __shared__ __align__(16) u16 sA[2][2][128 * 32];  // 32 KiB
  __shared__ __align__(16) u16 sB[2][2][256 * 32];  // 64 KiB

  const int tid = threadIdx.x;
  const int lane = tid & 63, wave = tid >> 6;
  const int quad = lane >> 4, l16 = lane & 15;

  // bijective XCD swizzle: 768 = 8 XCD x 96 contiguous tiles
  const int lin = blockIdx.y * 12 + blockIdx.x;
  const int swz = (lin & 7) * 96 + (lin >> 3);
  const int bn = swz % 12, bm = swz / 12;
  const int m0 = bm * 128, n0 = bn * 256;
  const int wm = (wave >> 2) * 64, wn = (wave & 3) * 64;

  // staging (R4/R7 algebra): rows = base + (lane>>2), src 16B-group swizzled
  const int sRow = lane >> 2;
  const int sGrp = (lane & 3) ^ ((lane >> 3) & 3);
  const size_t aSrc = (size_t)(m0 + wave * 16 + sRow) * 1024 + sGrp * 8;
  const size_t bSrc = (size_t)(n0 + wave * 32 + sRow) * 1024 + sGrp * 8;

  // read side (R4 constants): phys 16B-slot = quad ^ ((l16>>1)&3)
  const int swr = (quad ^ ((l16 >> 1) & 3)) * 8;
  const unsigned aRd = (unsigned)(size_t)&sA[0][0][0] +
                       (unsigned)(((wm + l16) * 32 + swr) * 2);
  const unsigned bRd = (unsigned)(size_t)&sB[0][0][0] +
                       (unsigned)(((wn + l16) * 32 + swr) * 2);

  f32x4 acc[4][4] = {};
  bf16x8 afr[4], bfr[4];

  STAGE_A(0, 0, 0); STAGE_B(0, 0, 0); STAGE_A(0, 1, 0); STAGE_B(0, 1, 0);
  QKV_VMW(0);
  QKV_BAR;

  for (int t = 0; t < 16; ++t) {
    const int d = t & 1, dn = d ^ 1;
    const bool pf = (t < 15);
    // sA khalf stride 8192 B, dbuf 16384 B; sB khalf 16384 B, dbuf 32768 B
    const unsigned a0 = aRd + (unsigned)(d * 16384);
    const unsigned b0 = bRd + (unsigned)(d * 32768);

    if (pf) { STAGE_A(dn, 0, t + 1); STAGE_B(dn, 0, t + 1); }
    LDB_ALL(b0); LDA_ALL(a0);
    QKV_LGK0;
    SCHED0;
    __builtin_amdgcn_s_setprio(1);
    MMA4;
    __builtin_amdgcn_s_setprio(0);
    SCHED0;

    if (pf) { STAGE_A(dn, 1, t + 1); STAGE_B(dn, 1, t + 1); }
    LDB_ALL(b0 + 16384u); LDA_ALL(a0 + 8192u);
    QKV_LGK0;
    SCHED0;
    __builtin_amdgcn_s_setprio(1);
    MMA4;
    __builtin_amdgcn_s_setprio(0);
    SCHED0;

    QKV_VMW(0);
    QKV_BAR;
  }

  const int proj = bn >> 2;  // 4 column-tiles per projection (wave-uniform)
#pragma unroll
  for (int mt = 0; mt < 4; ++mt) {
#pragma unroll
    for (int nt = 0; nt < 4; ++nt) {
#pragma unroll
      for (int r = 0; r < 4; ++r) {
        int mrow = m0 + wm + mt * 16 + quad * 4 + r;
        int nloc = (n0 & 1023) + wn + nt * 16 + l16;
        u16 bv = f32_to_bf16(acc[mt][nt][r]);
        if (proj == 0) {
          Q[(size_t)mrow * 1024 + nloc] = bv;
        } else if (proj == 1) {
          K[(size_t)mrow * 1024 + nloc] = bv;
        } else {
          // mrow = b*2048 + t ; nloc = h*64 + d -> Vt[((b*16+h)*64+d)*2048 + t]
          int b = mrow >> 11, tt = mrow & 2047;
          int h = nloc >> 6, dd = nloc & 63;
          Vt[((size_t)((b * 16 + h) * 64 + dd)) * 2048 + tt] = bv;
        }
      }
    }
  }
}

#undef STAGE_A
#undef STAGE_B
#undef MMA4
#undef LDA_ALL
#undef LDB_ALL

// ======================================================================
// out-projection GEMM: out_f32(8192,1024) = Ctx(8192,1024) @ WoT^T
// R7 structure (validated), unchanged.
// ======================================================================

#define LDA_ALL(ad) { DSR(afr[0], ad, 0);    DSR(afr[1], ad, 1024); \
                      DSR(afr[2], ad, 2048); DSR(afr[3], ad, 3072); }
#define LDB_ALL(bd) { DSR(bfr[0], bd, 0);    DSR(bfr[1], bd, 1024); \
                      DSR(bfr[2], bd, 2048); DSR(bfr[3], bd, 3072); }
#define OSTAGE_A(d2, kh, kt)                                            \
    gl_lds16(A + aSrc + (size_t)(kt) * 64 + (kh) * 32,                  \
             &sA[d2][kh][wave * 512])
#define OSTAGE_B(d2, kh, kt) do {                                       \
    const u16* _p = Bt + bSrc + (size_t)(kt) * 64 + (kh) * 32;          \
    gl_lds16(_p, &sB[d2][kh][wave * 1024]);                             \
    gl_lds16(_p + 16 * 1024, &sB[d2][kh][wave * 1024 + 512]);           \
  } while (0)
#define OMMA {                                                          \
    _Pragma("unroll") for (int mt = 0; mt < 4; ++mt)                    \
      _Pragma("unroll") for (int nt = 0; nt < 4; ++nt)                  \
        acc[mt][nt] = __builtin_amdgcn_mfma_f32_16x16x32_bf16(          \
            afr[mt], bfr[nt], acc[mt][nt], 0, 0, 0); }

__global__ __launch_bounds__(512, 2) void gemm_out_kernel(const u16* __restrict__ A,
                                                          const u16* __restrict__ Bt,
                                                          float* __restrict__ C) {
  __shared__ __align__(16) u16 sA[2][2][128 * 32];  // 32 KiB
  __shared__ __align__(16) u16 sB[2][2][256 * 32];  // 64 KiB

  const int tid = threadIdx.x;
  const int lane = tid & 63, wave = tid >> 6;
  const int quad = lane >> 4, l16 = lane & 15;

  // bijective XCD swizzle: 256 = 8 XCD x 32 contiguous tiles
  const int lin = blockIdx.y * 4 + blockIdx.x;
  const int swz = (lin & 7) * 32 + (lin >> 3);
  const int bn = swz & 3, bm = swz >> 2;
  const int m0 = bm * 128, n0 = bn * 256;
  const int wm = (wave >> 2) * 64, wn = (wave & 3) * 64;

  // staging (R4 algebra): rows = base + (lane>>2), src 16B-group swizzled
  const int sRow = lane >> 2;
  const int sGrp = (lane & 3) ^ ((lane >> 3) & 3);
  const size_t aSrc = (size_t)(m0 + wave * 16 + sRow) * 1024 + sGrp * 8;
  const size_t bSrc = (size_t)(n0 + wave * 32 + sRow) * 1024 + sGrp * 8;

  // read side (R4 constants): phys 16B-slot = quad ^ ((l16>>1)&3)
  const int swr = (quad ^ ((l16 >> 1) & 3)) * 8;
  const unsigned aRd = (unsigned)(size_t)&sA[0][0][0] +
                       (unsigned)(((wm + l16) * 32 + swr) * 2);
  const unsigned bRd = (unsigned)(size_t)&sB[0][0][0] +
                       (unsigned)(((wn + l16) * 32 + swr) * 2);

  f32x4 acc[4][4] = {};
  bf16x8 afr[4], bfr[4];

  OSTAGE_A(0, 0, 0); OSTAGE_B(0, 0, 0); OSTAGE_A(0, 1, 0); OSTAGE_B(0, 1, 0);
  QKV_VMW(0);
  QKV_BAR;

  for (int t = 0; t < 16; ++t) {
    const int d = t & 1, dn = d ^ 1;
    const bool pf = (t < 15);
    // sA khalf stride 8192 B, dbuf 16384 B; sB khalf 16384 B, dbuf 32768 B
    const unsigned a0 = aRd + (unsigned)(d * 16384);
    const unsigned b0 = bRd + (unsigned)(d * 32768);

    if (pf) { OSTAGE_A(dn, 0, t + 1); OSTAGE_B(dn, 0, t + 1); }
    LDB_ALL(b0); LDA_ALL(a0);
    QKV_LGK0;
    SCHED0;
    __builtin_amdgcn_s_setprio(1);
    OMMA;
    __builtin_amdgcn_s_setprio(0);
    SCHED0;

    if (pf) { OSTAGE_A(dn, 1, t + 1); OSTAGE_B(dn, 1, t + 1); }
    LDB_ALL(b0 + 16384u); LDA_ALL(a0 + 8192u);
    QKV_LGK0;
    SCHED0;
    __builtin_amdgcn_s_setprio(1);
    OMMA;
    __builtin_amdgcn_s_setprio(0);
    SCHED0;

    QKV_VMW(0);
    QKV_BAR;
  }

#pragma unroll
  for (int mt = 0; mt < 4; ++mt)
#pragma unroll
    for (int nt = 0; nt < 4; ++nt)
#pragma unroll
      for (int r = 0; r < 4; ++r) {
        int mrow = m0 + wm + mt * 16 + quad * 4 + r;
        int ncol = n0 + wn + nt * 16 + l16;
        C[(size_t)mrow * 1024 + ncol] = acc[mt][nt][r];
      }
}

#undef OSTAGE_A
#undef OSTAGE_B
#undef LDA_ALL
#undef LDB_ALL
#undef OMMA

// ---------------- flash attention (causal, balanced pairs) ----------------
// Proven R0-R5 version, FROZEN (R6's reg-prefetch spilled: WRITE 313MB).
#define LDS_S 72  // padded stride for 64-wide tiles (144B, 16B-aligned)

__global__ __launch_bounds__(256, 4) void attn_kernel(const u16* __restrict__ Qm,
                                                      const u16* __restrict__ Km,
                                                      const u16* __restrict__ Vt,
                                                      u16* __restrict__ Ctx) {
  const int pi = blockIdx.x;  // pair index 0..15
  const int h = blockIdx.y, b = blockIdx.z;
  const int tid = threadIdx.x, lane = tid & 63, wave = tid >> 6;
  const int quad = lane >> 4, l16 = lane & 15;
  const int q64[2] = {pi, 31 - pi};  // light, heavy 64-row Q-tile indices

  __shared__ __align__(16) u16 sK[64 * LDS_S];
  __shared__ __align__(16) u16 sV[64 * LDS_S];
  __shared__ __align__(16) u16 sP[4][2][16 * LDS_S];  // per (wave, s): ILP

  // Q fragments: qf[s][kk], rows q64[s]*64 + wave*16 + l16
  bf16x8 qf[2][2];
#pragma unroll
  for (int s = 0; s < 2; ++s) {
    const size_t qrow = (size_t)(b * 2048 + q64[s] * 64 + wave * 16 + l16);
#pragma unroll
    for (int kk = 0; kk < 2; ++kk)
      qf[s][kk] = *(const bf16x8*)(Qm + qrow * 1024 + h * 64 + kk * 32 + quad * 8);
  }

  f32x4 o_acc[2][4] = {};
  float ps[2][4] = {};  // per-lane partial softmax sums

  const int nkt = 32 - pi;  // k-tiles 0..(31-pi) cover heavy tile's range
  for (int kt = 0; kt < nkt; ++kt) {
    const int k0 = kt * 64;
    __syncthreads();
#pragma unroll
    for (int i = 0; i < 2; ++i) {
      int c = tid + 256 * i;
      int row = c >> 3, col = (c & 7) * 8;
      *(uint4*)(sK + row * LDS_S + col) =
          *(const uint4*)(Km + ((size_t)(b * 2048 + k0 + row)) * 1024 + h * 64 + col);
      *(uint4*)(sV + row * LDS_S + col) =
          *(const uint4*)(Vt + ((size_t)((b * 16 + h) * 64 + row)) * 2048 + k0 + col);
    }
    __syncthreads();

#pragma unroll
    for (int s = 0; s < 2; ++s) {
      const int qmin = q64[s] * 64 + wave * 16;  // wave-uniform
      if (k0 > qmin + 15) continue;              // fully-masked subtile

      // S = Q K^T (16q x 64k)
      f32x4 sc[4];
#pragma unroll
      for (int nt = 0; nt < 4; ++nt) {
        f32x4 a = {};
#pragma unroll
        for (int kk = 0; kk < 2; ++kk) {
          bf16x8 kf = *(const bf16x8*)(sK + (nt * 16 + l16) * LDS_S + kk * 32 + quad * 8);
          a = __builtin_amdgcn_mfma_f32_16x16x32_bf16(qf[s][kk], kf, a, 0, 0, 0);
        }
        sc[nt] = a;
      }

      // scale + causal mask (diagonal tiles only) + exp; sums in-register
      const bool need_mask = (k0 + 63) > qmin;
#pragma unroll
      for (int nt = 0; nt < 4; ++nt) {
#pragma unroll
        for (int r = 0; r < 4; ++r) {
          float v = sc[nt][r] * 0.125f;
          if (need_mask) {
            int qi = qmin + quad * 4 + r;
            int kj = k0 + nt * 16 + l16;
            if (kj > qi) v = -1e30f;
          }
          float p = __expf(v);  // masked -> 0
          sc[nt][r] = p;
          ps[s][r] += p;
        }
      }

      // P: C-layout -> LDS (RNE bf16) -> A-layout; per-(wave,s) region,
      // same-wave DS ops in-order, no barrier needed.
#pragma unroll
      for (int nt = 0; nt < 4; ++nt)
#pragma unroll
        for (int r = 0; r < 4; ++r)
          sP[wave][s][(quad * 4 + r) * LDS_S + nt * 16 + l16] = f32_to_bf16(sc[nt][r]);

#pragma unroll
      for (int kk = 0; kk < 2; ++kk) {
        bf16x8 pf = *(const bf16x8*)(sP[wave][s] + l16 * LDS_S + kk * 32 + quad * 8);
#pragma unroll
        for (int dt = 0; dt < 4; ++dt) {
          bf16x8 vf = *(const bf16x8*)(sV + (dt * 16 + l16) * LDS_S + kk * 32 + quad * 8);
          o_acc[s][dt] = __builtin_amdgcn_mfma_f32_16x16x32_bf16(pf, vf,
                                                                 o_acc[s][dt], 0, 0, 0);
        }
      }
    }
  }

  // one 16-lane reduction per (s,r) — once per kernel
  float inv_l[2][4];
#pragma unroll
  for (int s = 0; s < 2; ++s)
#pragma unroll
    for (int r = 0; r < 4; ++r)
      inv_l[s][r] = 1.0f / red16_sum(ps[s][r]);

  // epilogue: Ctx[b*2048+t][h*64+d]
#pragma unroll
  for (int s = 0; s < 2; ++s)
#pragma unroll
    for (int dt = 0; dt < 4; ++dt)
#pragma unroll
      for (int r = 0; r < 4; ++r) {
        int trow = q64[s] * 64 + wave * 16 + quad * 4 + r;
        Ctx[((size_t)(b * 2048 + trow)) * 1024 + h * 64 + dt * 16 + l16] =
            f32_to_bf16(o_acc[s][dt][r] * inv_l[s][r]);
      }
}

// ---------------- launcher ----------------
extern "C" void kernel_launch(void* const* d_in, const int* in_sizes, int n_in,
                              void* d_out, int out_size, void* d_ws, size_t ws_size,
                              hipStream_t stream) {
  const float* x  = (const float*)d_in[0];
  const float* wq = (const float*)d_in[1];
  const float* wk = (const float*)d_in[2];
  const float* wv = (const float*)d_in[3];
  const float* wo = (const float*)d_in[4];
  u16* ws = (u16*)d_ws;

  u16* wtqkv = ws;                          // wtq|wtk|wtv contiguous (3M elems)
  u16* wto  = ws + 3 * (size_t)(1 << 20);
  u16* Q    = ws + 4 * (size_t)(1 << 20);   // 8M elems each
  u16* K    = ws + 12 * (size_t)(1 << 20);
  u16* Vt   = ws + 20 * (size_t)(1 << 20);
  u16* Ctx  = ws + 28 * (size_t)(1 << 20);
  u16* xb   = Ctx;  // alias: xb dead before attn writes Ctx
  float* out = (float*)d_out;

  dim3 tb(256);
  xcvt_kernel<<<dim3(4096), tb, 0, stream>>>(x, xb);
  transpose_cvt4_kernel<<<dim3(32, 32, 4), tb, 0, stream>>>(wq, wk, wv, wo, ws);

  gemm_qkv_kernel<<<dim3(12, 64), dim3(512), 0, stream>>>(xb, wtqkv, Q, K, Vt);

  attn_kernel<<<dim3(16, 16, 4), tb, 0, stream>>>(Q, K, Vt, Ctx);

  gemm_out_kernel<<<dim3(4, 64), dim3(512), 0, stream>>>(Ctx, wto, out);
}

// Round 10
// 285.305 us; speedup vs baseline: 1.0394x; 1.0394x over previous
//
#include <hip/hip_runtime.h>

typedef unsigned short u16;
typedef short bf16x8 __attribute__((ext_vector_type(8)));
typedef float f32x4 __attribute__((ext_vector_type(4)));

__device__ inline u16 f32_to_bf16(float f) {
  union { float f; unsigned int u; } v; v.f = f;
  unsigned int r = v.u + 0x7FFFu + ((v.u >> 16) & 1u);
  return (u16)(r >> 16);
}

// 16-lane butterfly sum via __shfl_xor (HW-proven) — used ONCE per kernel.
__device__ inline float red16_sum(float x) {
#pragma unroll
  for (int m = 8; m >= 1; m >>= 1) x += __shfl_xor(x, m);
  return x;
}

// async global->LDS, 16B per lane; LDS dest = wave-uniform base + lane*16.
__device__ __forceinline__ void gl_lds16(const u16* g, u16* l) {
  __builtin_amdgcn_global_load_lds(
      (const __attribute__((address_space(1))) void*)g,
      (__attribute__((address_space(3))) void*)l, 16, 0, 0);
}

// ------- x convert: f32 -> bf16, 8 elems/thread -------
__global__ __launch_bounds__(256) void xcvt_kernel(const float* __restrict__ in,
                                                   u16* __restrict__ out) {
  size_t i = (size_t)blockIdx.x * 256 + threadIdx.x;
  float4 f0 = ((const float4*)in)[2 * i];
  float4 f1 = ((const float4*)in)[2 * i + 1];
  union { u16 t[8]; uint4 v; } pk;
  pk.t[0] = f32_to_bf16(f0.x); pk.t[1] = f32_to_bf16(f0.y);
  pk.t[2] = f32_to_bf16(f0.z); pk.t[3] = f32_to_bf16(f0.w);
  pk.t[4] = f32_to_bf16(f1.x); pk.t[5] = f32_to_bf16(f1.y);
  pk.t[6] = f32_to_bf16(f1.z); pk.t[7] = f32_to_bf16(f1.w);
  ((uint4*)out)[i] = pk.v;
}

// ------- 4x transpose+convert 1024x1024 (z = which matrix) -------
__global__ __launch_bounds__(256) void transpose_cvt4_kernel(const float* __restrict__ i0,
                                                             const float* __restrict__ i1,
                                                             const float* __restrict__ i2,
                                                             const float* __restrict__ i3,
                                                             u16* __restrict__ wbase) {
  const int z = blockIdx.z;
  const float* in = (z == 0) ? i0 : (z == 1) ? i1 : (z == 2) ? i2 : i3;
  u16* out = wbase + (size_t)z * (1 << 20);
  __shared__ __align__(16) float tile[32][33];
  const int tx = threadIdx.x & 31, ty = threadIdx.x >> 5; // 32 x 8
  const int bx = blockIdx.x * 32, by = blockIdx.y * 32;
#pragma unroll
  for (int i = 0; i < 32; i += 8)
    tile[ty + i][tx] = in[(size_t)(by + ty + i) * 1024 + bx + tx];
  __syncthreads();
#pragma unroll
  for (int i = 0; i < 32; i += 8)
    out[(size_t)(bx + ty + i) * 1024 + by + tx] = f32_to_bf16(tile[tx][ty + i]);
}

// ======================================================================
// fused QKV GEMM — R10 (= R9 resubmit; R9 bench was a container-level
// failure, not a kernel result — audit found no crash/hang vector).
// 256x256 tile, 16 waves x (64x64 output each).
// [Q|K|V](8192,3072) = xb(8192,1024) @ Bt(3072,1024)^T
//
// Occupancy theory: R4 (8 waves, acc 128 AGPR/wave -> ~220 unified regs)
// ran at 2 waves/SIMD; schedule variants R2/R3/R4 all converged ~95-100us
// because nothing hides the lgkm/barrier gaps at that occupancy.  Keep the
// tile (reuse: FETCH 59.6MB) and all R4 swizzle algebra (conflicts=0
// pedigree) but split into 16 waves: acc[4][4] = 64 regs/wave -> ~110
// unified -> 4 waves/SIMD (2x occupancy).  Staging khalf-granular: one
// 16 KB khalf (256x32) = exactly one gl_lds16 per thread (1024 thr x 16B);
// 2-buffer depth-1 pipeline, one vmcnt(0)+s_barrier per khalf (R4's proven
// pattern at half granularity).  LDS 64 KiB.
// ======================================================================

#define QKV_BAR asm volatile("s_barrier" ::: "memory")
#define QKV_VMW(n) asm volatile("s_waitcnt vmcnt(" #n ")" ::: "memory")
#define QKV_LGK0 asm volatile("s_waitcnt lgkmcnt(0)" ::: "memory")
#define SCHED0 __builtin_amdgcn_sched_barrier(0)

// asm ds_read_b128: dst = 4-VGPR tuple, addr = LDS byte address, literal offset
#define DSR(dst, addr, off) \
  asm volatile("ds_read_b128 %0, %1 offset:" #off : "=v"(dst) : "v"(addr))

// 64 B rows (one khalf); frags 16 rows apart -> 1024 B
#define LDA_ALL(ad) { DSR(afr[0], ad, 0);    DSR(afr[1], ad, 1024); \
                      DSR(afr[2], ad, 2048); DSR(afr[3], ad, 3072); }
#define LDB_ALL(bd) { DSR(bfr[0], bd, 0);    DSR(bfr[1], bd, 1024); \
                      DSR(bfr[2], bd, 2048); DSR(bfr[3], bd, 3072); }

#define QSTAGE_A(p, kh) gl_lds16(A + aSrc + (size_t)(kh) * 32, &sA[p][wave * 512])
#define QSTAGE_B(p, kh) gl_lds16(Bt + bSrc + (size_t)(kh) * 32, &sB[p][wave * 512])
#define MMA16 {                                                    \
    _Pragma("unroll") for (int mt = 0; mt < 4; ++mt)               \
      _Pragma("unroll") for (int nt = 0; nt < 4; ++nt)             \
        acc[mt][nt] = __builtin_amdgcn_mfma_f32_16x16x32_bf16(     \
            afr[mt], bfr[nt], acc[mt][nt], 0, 0, 0); }

__global__ __launch_bounds__(1024, 4) void gemm_qkv_kernel(const u16* __restrict__ A,
                                                           const u16* __restrict__ Bt,
                                                           u16* __restrict__ Q,
                                                           u16* __restrict__ K,
                                                           u16* __restrict__ Vt) {
  __shared__ __align__(16) u16 sA[2][256 * 32];  // 32 KiB
  __shared__ __align__(16) u16 sB[2][256 * 32];  // 32 KiB

  const int tid = threadIdx.x;
  const int lane = tid & 63, wave = tid >> 6;  // wave 0..15
  const int quad = lane >> 4, l16 = lane & 15;

  // bijective XCD swizzle: 384 = 8 XCD x 48 contiguous tiles (as R4)
  const int lin = blockIdx.y * 12 + blockIdx.x;
  const int swz = (lin & 7) * 48 + (lin >> 3);
  const int bn = swz % 12, bm = swz / 12;
  const int m0 = bm * 256, n0 = bn * 256;
  const int wm = (wave >> 2) * 64, wn = (wave & 3) * 64;

  // staging (R4 bit-algebra, tid-indexed): row = tid>>2, phys slot = tid&3,
  // source 16B-group = phys ^ ((row>>1)&3) = (tid&3)^((tid>>3)&3)
  // -> wave w, lane l lands at LDS byte w*1024 + l*16 (linear, DMA-legal)
  const int srow = tid >> 2;
  const int sgrp = (tid & 3) ^ ((tid >> 3) & 3);
  const size_t aSrc = (size_t)(m0 + srow) * 1024 + sgrp * 8;
  const size_t bSrc = (size_t)(n0 + srow) * 1024 + sgrp * 8;

  // read side (R4 constants): phys 16B-slot = quad ^ ((l16>>1)&3)
  const int swr = (quad ^ ((l16 >> 1) & 3)) * 8;
  const unsigned aRd = (unsigned)(size_t)&sA[0][0] +
                       (unsigned)(((wm + l16) * 32 + swr) * 2);
  const unsigned bRd = (unsigned)(size_t)&sB[0][0] +
                       (unsigned)(((wn + l16) * 32 + swr) * 2);

  f32x4 acc[4][4] = {};
  bf16x8 afr[4], bfr[4];

  // prologue: stage khalf 0; drain; publish
  QSTAGE_A(0, 0); QSTAGE_B(0, 0);
  QKV_VMW(0);
  QKV_BAR;

  for (int kh = 0; kh < 32; ++kh) {
    const int p = kh & 1, pn = p ^ 1;
    const bool pf = (kh < 31);
    const unsigned a0 = aRd + (unsigned)(p * 16384);  // buf stride 16 KiB
    const unsigned b0 = bRd + (unsigned)(p * 16384);

    if (pf) { QSTAGE_A(pn, kh + 1); QSTAGE_B(pn, kh + 1); }
    LDB_ALL(b0); LDA_ALL(a0);
    QKV_LGK0;
    SCHED0;
    __builtin_amdgcn_s_setprio(1);
    MMA16;
    __builtin_amdgcn_s_setprio(0);
    SCHED0;

    // own 2 DMAs for kh+1 drained, then publish buf[pn] / license buf reuse
    QKV_VMW(0);
    QKV_BAR;
  }

  const int proj = bn >> 2;  // 4 column-tiles per projection (wave-uniform)
#pragma unroll
  for (int mt = 0; mt < 4; ++mt) {
#pragma unroll
    for (int nt = 0; nt < 4; ++nt) {
#pragma unroll
      for (int r = 0; r < 4; ++r) {
        int mrow = m0 + wm + mt * 16 + quad * 4 + r;
        int nloc = (n0 & 1023) + wn + nt * 16 + l16;
        u16 bv = f32_to_bf16(acc[mt][nt][r]);
        if (proj == 0) {
          Q[(size_t)mrow * 1024 + nloc] = bv;
        } else if (proj == 1) {
          K[(size_t)mrow * 1024 + nloc] = bv;
        } else {
          // mrow = b*2048 + t ; nloc = h*64 + d -> Vt[((b*16+h)*64+d)*2048 + t]
          int b = mrow >> 11, tt = mrow & 2047;
          int h = nloc >> 6, dd = nloc & 63;
          Vt[((size_t)((b * 16 + h) * 64 + dd)) * 2048 + tt] = bv;
        }
      }
    }
  }
}

#undef QSTAGE_A
#undef QSTAGE_B
#undef MMA16

// ======================================================================
// out-projection GEMM: out_f32(8192,1024) = Ctx(8192,1024) @ WoT^T
// R7 structure (validated), unchanged.
// ======================================================================

#define OSTAGE_A(d2, kh, kt)                                            \
    gl_lds16(A + aSrc + (size_t)(kt) * 64 + (kh) * 32,                  \
             &sA[d2][kh][wave * 512])
#define OSTAGE_B(d2, kh, kt) do {                                       \
    const u16* _p = Bt + bSrc + (size_t)(kt) * 64 + (kh) * 32;          \
    gl_lds16(_p, &sB[d2][kh][wave * 1024]);                             \
    gl_lds16(_p + 16 * 1024, &sB[d2][kh][wave * 1024 + 512]);           \
  } while (0)
#define OMMA {                                                          \
    _Pragma("unroll") for (int mt = 0; mt < 4; ++mt)                    \
      _Pragma("unroll") for (int nt = 0; nt < 4; ++nt)                  \
        acc[mt][nt] = __builtin_amdgcn_mfma_f32_16x16x32_bf16(          \
            afr[mt], bfr[nt], acc[mt][nt], 0, 0, 0); }

__global__ __launch_bounds__(512, 2) void gemm_out_kernel(const u16* __restrict__ A,
                                                          const u16* __restrict__ Bt,
                                                          float* __restrict__ C) {
  __shared__ __align__(16) u16 sA[2][2][128 * 32];  // 32 KiB
  __shared__ __align__(16) u16 sB[2][2][256 * 32];  // 64 KiB

  const int tid = threadIdx.x;
  const int lane = tid & 63, wave = tid >> 6;
  const int quad = lane >> 4, l16 = lane & 15;

  // bijective XCD swizzle: 256 = 8 XCD x 32 contiguous tiles
  const int lin = blockIdx.y * 4 + blockIdx.x;
  const int swz = (lin & 7) * 32 + (lin >> 3);
  const int bn = swz & 3, bm = swz >> 2;
  const int m0 = bm * 128, n0 = bn * 256;
  const int wm = (wave >> 2) * 64, wn = (wave & 3) * 64;

  // staging (R4 algebra): rows = base + (lane>>2), src 16B-group swizzled
  const int sRow = lane >> 2;
  const int sGrp = (lane & 3) ^ ((lane >> 3) & 3);
  const size_t aSrc = (size_t)(m0 + wave * 16 + sRow) * 1024 + sGrp * 8;
  const size_t bSrc = (size_t)(n0 + wave * 32 + sRow) * 1024 + sGrp * 8;

  // read side (R4 constants): phys 16B-slot = quad ^ ((l16>>1)&3)
  const int swr = (quad ^ ((l16 >> 1) & 3)) * 8;
  const unsigned aRd = (unsigned)(size_t)&sA[0][0][0] +
                       (unsigned)(((wm + l16) * 32 + swr) * 2);
  const unsigned bRd = (unsigned)(size_t)&sB[0][0][0] +
                       (unsigned)(((wn + l16) * 32 + swr) * 2);

  f32x4 acc[4][4] = {};
  bf16x8 afr[4], bfr[4];

  OSTAGE_A(0, 0, 0); OSTAGE_B(0, 0, 0); OSTAGE_A(0, 1, 0); OSTAGE_B(0, 1, 0);
  QKV_VMW(0);
  QKV_BAR;

  for (int t = 0; t < 16; ++t) {
    const int d = t & 1, dn = d ^ 1;
    const bool pf = (t < 15);
    // sA khalf stride 8192 B, dbuf 16384 B; sB khalf 16384 B, dbuf 32768 B
    const unsigned a0 = aRd + (unsigned)(d * 16384);
    const unsigned b0 = bRd + (unsigned)(d * 32768);

    if (pf) { OSTAGE_A(dn, 0, t + 1); OSTAGE_B(dn, 0, t + 1); }
    LDB_ALL(b0); LDA_ALL(a0);
    QKV_LGK0;
    SCHED0;
    __builtin_amdgcn_s_setprio(1);
    OMMA;
    __builtin_amdgcn_s_setprio(0);
    SCHED0;

    if (pf) { OSTAGE_A(dn, 1, t + 1); OSTAGE_B(dn, 1, t + 1); }
    LDB_ALL(b0 + 16384u); LDA_ALL(a0 + 8192u);
    QKV_LGK0;
    SCHED0;
    __builtin_amdgcn_s_setprio(1);
    OMMA;
    __builtin_amdgcn_s_setprio(0);
    SCHED0;

    QKV_VMW(0);
    QKV_BAR;
  }

#pragma unroll
  for (int mt = 0; mt < 4; ++mt)
#pragma unroll
    for (int nt = 0; nt < 4; ++nt)
#pragma unroll
      for (int r = 0; r < 4; ++r) {
        int mrow = m0 + wm + mt * 16 + quad * 4 + r;
        int ncol = n0 + wn + nt * 16 + l16;
        C[(size_t)mrow * 1024 + ncol] = acc[mt][nt][r];
      }
}

#undef OSTAGE_A
#undef OSTAGE_B
#undef OMMA

// ---------------- flash attention (causal, balanced pairs) ----------------
// Proven R0-R5 version, FROZEN (R6's reg-prefetch spilled: WRITE 313MB).
#define LDS_S 72  // padded stride for 64-wide tiles (144B, 16B-aligned)

__global__ __launch_bounds__(256, 4) void attn_kernel(const u16* __restrict__ Qm,
                                                      const u16* __restrict__ Km,
                                                      const u16* __restrict__ Vt,
                                                      u16* __restrict__ Ctx) {
  const int pi = blockIdx.x;  // pair index 0..15
  const int h = blockIdx.y, b = blockIdx.z;
  const int tid = threadIdx.x, lane = tid & 63, wave = tid >> 6;
  const int quad = lane >> 4, l16 = lane & 15;
  const int q64[2] = {pi, 31 - pi};  // light, heavy 64-row Q-tile indices

  __shared__ __align__(16) u16 sK[64 * LDS_S];
  __shared__ __align__(16) u16 sV[64 * LDS_S];
  __shared__ __align__(16) u16 sP[4][2][16 * LDS_S];  // per (wave, s): ILP

  // Q fragments: qf[s][kk], rows q64[s]*64 + wave*16 + l16
  bf16x8 qf[2][2];
#pragma unroll
  for (int s = 0; s < 2; ++s) {
    const size_t qrow = (size_t)(b * 2048 + q64[s] * 64 + wave * 16 + l16);
#pragma unroll
    for (int kk = 0; kk < 2; ++kk)
      qf[s][kk] = *(const bf16x8*)(Qm + qrow * 1024 + h * 64 + kk * 32 + quad * 8);
  }

  f32x4 o_acc[2][4] = {};
  float ps[2][4] = {};  // per-lane partial softmax sums

  const int nkt = 32 - pi;  // k-tiles 0..(31-pi) cover heavy tile's range
  for (int kt = 0; kt < nkt; ++kt) {
    const int k0 = kt * 64;
    __syncthreads();
#pragma unroll
    for (int i = 0; i < 2; ++i) {
      int c = tid + 256 * i;
      int row = c >> 3, col = (c & 7) * 8;
      *(uint4*)(sK + row * LDS_S + col) =
          *(const uint4*)(Km + ((size_t)(b * 2048 + k0 + row)) * 1024 + h * 64 + col);
      *(uint4*)(sV + row * LDS_S + col) =
          *(const uint4*)(Vt + ((size_t)((b * 16 + h) * 64 + row)) * 2048 + k0 + col);
    }
    __syncthreads();

#pragma unroll
    for (int s = 0; s < 2; ++s) {
      const int qmin = q64[s] * 64 + wave * 16;  // wave-uniform
      if (k0 > qmin + 15) continue;              // fully-masked subtile

      // S = Q K^T (16q x 64k)
      f32x4 sc[4];
#pragma unroll
      for (int nt = 0; nt < 4; ++nt) {
        f32x4 a = {};
#pragma unroll
        for (int kk = 0; kk < 2; ++kk) {
          bf16x8 kf = *(const bf16x8*)(sK + (nt * 16 + l16) * LDS_S + kk * 32 + quad * 8);
          a = __builtin_amdgcn_mfma_f32_16x16x32_bf16(qf[s][kk], kf, a, 0, 0, 0);
        }
        sc[nt] = a;
      }

      // scale + causal mask (diagonal tiles only) + exp; sums in-register
      const bool need_mask = (k0 + 63) > qmin;
#pragma unroll
      for (int nt = 0; nt < 4; ++nt) {
#pragma unroll
        for (int r = 0; r < 4; ++r) {
          float v = sc[nt][r] * 0.125f;
          if (need_mask) {
            int qi = qmin + quad * 4 + r;
            int kj = k0 + nt * 16 + l16;
            if (kj > qi) v = -1e30f;
          }
          float p = __expf(v);  // masked -> 0
          sc[nt][r] = p;
          ps[s][r] += p;
        }
      }

      // P: C-layout -> LDS (RNE bf16) -> A-layout; per-(wave,s) region,
      // same-wave DS ops in-order, no barrier needed.
#pragma unroll
      for (int nt = 0; nt < 4; ++nt)
#pragma unroll
        for (int r = 0; r < 4; ++r)
          sP[wave][s][(quad * 4 + r) * LDS_S + nt * 16 + l16] = f32_to_bf16(sc[nt][r]);

#pragma unroll
      for (int kk = 0; kk < 2; ++kk) {
        bf16x8 pf = *(const bf16x8*)(sP[wave][s] + l16 * LDS_S + kk * 32 + quad * 8);
#pragma unroll
        for (int dt = 0; dt < 4; ++dt) {
          bf16x8 vf = *(const bf16x8*)(sV + (dt * 16 + l16) * LDS_S + kk * 32 + quad * 8);
          o_acc[s][dt] = __builtin_amdgcn_mfma_f32_16x16x32_bf16(pf, vf,
                                                                 o_acc[s][dt], 0, 0, 0);
        }
      }
    }
  }

  // one 16-lane reduction per (s,r) — once per kernel
  float inv_l[2][4];
#pragma unroll
  for (int s = 0; s < 2; ++s)
#pragma unroll
    for (int r = 0; r < 4; ++r)
      inv_l[s][r] = 1.0f / red16_sum(ps[s][r]);

  // epilogue: Ctx[b*2048+t][h*64+d]
#pragma unroll
  for (int s = 0; s < 2; ++s)
#pragma unroll
    for (int dt = 0; dt < 4; ++dt)
#pragma unroll
      for (int r = 0; r < 4; ++r) {
        int trow = q64[s] * 64 + wave * 16 + quad * 4 + r;
        Ctx[((size_t)(b * 2048 + trow)) * 1024 + h * 64 + dt * 16 + l16] =
            f32_to_bf16(o_acc[s][dt][r] * inv_l[s][r]);
      }
}

// ---------------- launcher ----------------
extern "C" void kernel_launch(void* const* d_in, const int* in_sizes, int n_in,
                              void* d_out, int out_size, void* d_ws, size_t ws_size,
                              hipStream_t stream) {
  const float* x  = (const float*)d_in[0];
  const float* wq = (const float*)d_in[1];
  const float* wk = (const float*)d_in[2];
  const float* wv = (const float*)d_in[3];
  const float* wo = (const float*)d_in[4];
  u16* ws = (u16*)d_ws;

  u16* wtqkv = ws;                          // wtq|wtk|wtv contiguous (3M elems)
  u16* wto  = ws + 3 * (size_t)(1 << 20);
  u16* Q    = ws + 4 * (size_t)(1 << 20);   // 8M elems each
  u16* K    = ws + 12 * (size_t)(1 << 20);
  u16* Vt   = ws + 20 * (size_t)(1 << 20);
  u16* Ctx  = ws + 28 * (size_t)(1 << 20);
  u16* xb   = Ctx;  // alias: xb dead before attn writes Ctx
  float* out = (float*)d_out;

  dim3 tb(256);
  xcvt_kernel<<<dim3(4096), tb, 0, stream>>>(x, xb);
  transpose_cvt4_kernel<<<dim3(32, 32, 4), tb, 0, stream>>>(wq, wk, wv, wo, ws);

  gemm_qkv_kernel<<<dim3(12, 32), dim3(1024), 0, stream>>>(xb, wtqkv, Q, K, Vt);

  attn_kernel<<<dim3(16, 16, 4), tb, 0, stream>>>(Q, K, Vt, Ctx);

  gemm_out_kernel<<<dim3(4, 64), dim3(512), 0, stream>>>(Ctx, wto, out);
}